// Round 4
// baseline (331.275 us; speedup 1.0000x reference)
//
#include <hip/hip_runtime.h>
#include <hip/hip_bf16.h>

// TaylorMap, symmetric-packed quadratic, uniform-9 pair stream (bf16).
// R16 = R12 core (zero-spill shape, lgkm-only barriers from R15, QTAIL peel
// reverted) + HYBRID A-FILL: slices 0..3 of every pair arrive via
// global_load_lds DMA into a per-wave depth-2 LDS ring (no VGPR dest -> no
// WAR interlock with MFMA operand reads, no L1->VGPR return-port
// contention; m97-proven ~54 B/cyc/CU path), slices 4..8 stay on the
// direct global->VGPR path. Evidence: R13/R14/R15 overlap attempts all
// null; fill rate stuck at ~31 B/cyc/CU = 2.34 MB/step / 76k cyc -> the
// VGPR-return path is the binding resource, not barriers/lockstep.
// vmcnt discipline (T4): each pair body issues exactly 5 direct loads +
// 4 DMAs; 's_waitcnt vmcnt(9)' at pair top waits for the 2-pairs-ago DMA
// batch (oldest in flight) while keeping the previous body's 9 ops in
// flight -- the queue never drains below 4. asm memory clobbers fence
// cross-body issue order; one empty-asm fence pins the prologue batch.
// Y-chain consumes direct slots (4..7-BK) first, staged (0..3) last, so
// the pair-top ds_reads get ~4 MFMAs of latency cover.

#define DSTATE 128
#define BATCH  16384
#define NSTEPS 7
#define BT     64
#define NSL    585          // slices per d-tile: 64*9 pair + 8 linear + 1 pad

typedef __attribute__((ext_vector_type(8)))  short  short8;   // 8 bf16 = 4 VGPRs
typedef __attribute__((ext_vector_type(16))) float  f32x16;   // MFMA 32x32 C/D

__device__ __forceinline__ unsigned short f2bf(float f){
    unsigned int u = __float_as_uint(f);
    u += 0x7fff + ((u >> 16) & 1);          // RNE
    return (unsigned short)(u >> 16);
}

// lgkmcnt-only workgroup barrier: drains LDS ops, NOT the vmem queue.
__device__ __forceinline__ void barrier_lgkm(){
    asm volatile("s_waitcnt lgkmcnt(0)" ::: "memory");
    __builtin_amdgcn_s_barrier();
}

// global -> LDS DMA, 16 B per lane: dest = lds base + lane*16 (linear),
// src = per-lane global address (gp already has lane folded in).
#define GLL(gp, lp) __builtin_amdgcn_global_load_lds(                           \
        (const __attribute__((address_space(1))) void*)(gp),                    \
        (__attribute__((address_space(3))) void*)(lp), 16, 0, 0)

// Pack symmetric-folded W into bf16 MFMA-A fragments, uniform-9 pair stream.
// Pair p at positions 9p..9p+8: first 8-(p>>4) slices are row p (j-blocks
// p>>4..7), remaining 1+(p>>4) are row 127-p (j-blocks 7-(p>>4)..7).
// Fragment layout: A[m][k], m=lane&31 -> d=32t+m, k=(lane>>5)*8+e -> j=16*s+k.
__global__ void prep_kernel(const float* __restrict__ W, short8* __restrict__ A){
    int gid = blockIdx.x * 256 + threadIdx.x;
    const int ntotal = 4 * 130 * 8 * 64;
    if (gid >= ntotal) return;
    int lane = gid & 63; int r = gid >> 6;
    int s = r & 7;  r >>= 3;
    int row = r % 130;
    int t   = r / 130;
    int d  = t * 32 + (lane & 31);
    int kb = (lane >> 5) * 8;
    int dst;
    bool zero = false;
    if (row < 64){
        int sl = row >> 4;
        if (s < sl) return;
        dst = t * NSL + 9 * row + (s - sl);
    } else if (row < 128){
        int p  = 127 - row;
        int sl = row >> 4;
        if (s < sl) return;
        int ca = 8 - (p >> 4);
        dst = t * NSL + 9 * p + ca + (s - sl);
    } else if (row == 128){
        dst = t * NSL + 576 + s;               // linear (W1) row
    } else {
        if (s) return;                         // zero pad slice
        dst = t * NSL + 584;
        zero = true;
    }
    union { short8 v; unsigned short u[8]; } fr;
#pragma unroll
    for (int e = 0; e < 8; ++e){
        int j = s * 16 + kb + e;
        float v;
        if (zero) v = 0.0f;
        else if (row < 128){
            if      (j < row)  v = 0.0f;
            else if (j == row) v = W[(129 + 128 * row + j) * 128 + d];
            else               v = W[(129 + 128 * row + j) * 128 + d]
                                 + W[(129 + 128 * j + row) * 128 + d];
        } else {
            v = W[(1 + j) * 128 + d];
        }
        fr.u[e] = f2bf(v);
    }
    A[(size_t)dst * 64 + lane] = fr.v;
}

__global__ __launch_bounds__(512)
void taylor_kernel(const float* __restrict__ X, const float* __restrict__ W,
                   const float* __restrict__ tini, const float* __restrict__ lini,
                   const short8* __restrict__ A, float* __restrict__ out)
{
    __shared__ float  x_lds[DSTATE * BT];      // fp32 master state [d][b], 32 KB
    __shared__ float  w0_lds[DSTATE];
    __shared__ short8 bpack[2 * 8 * 64];       // B frags, 2 groups x 8 slices, 16 KB
    __shared__ float  sc_lds[2][4 * 64 * 17];  // K-merge scratch, 34.8 KB
    __shared__ short8 ring[8][2][4][64];       // A staging ring: wave x par x slice, 64 KB

    const int tid  = threadIdx.x;
    const int lane = tid & 63;
    const int w    = tid >> 6;
    const int t    = w & 3;                    // d-tile
    const int g    = w >> 2;                   // K-half (pairs 0..31 / 32..63+lin)
    const int ln   = lane & 31;
    const int hi   = lane >> 5;
    const int b0   = blockIdx.x * BT;

    // ---- init x0 = [X | t_init | l_init] ----
#pragma unroll
    for (int it = 0; it < 16; ++it){
        int entry = tid + it * 512;            // entry = b*128 + d
        int b = entry >> 7, d = entry & 127;
        float v;
        if      (d < 120) v = X[(b0 + b) * 120 + d];
        else if (d < 124) v = tini[d - 120];
        else              v = lini[d - 124];
        x_lds[d * BT + b] = v;
    }
    if (tid < DSTATE) w0_lds[tid] = W[tid];

    // wave's half-stream base: g0 -> slice 0, g1 -> slice 288 (pair 32)
    const short8* const Aw = A + ((size_t)t * NSL + (size_t)g * 288) * 64 + lane;
    const f32x16 zero16 = {};

    // ring pointers: read side (per-lane), DMA dest side (wave-uniform)
    const short8* const rring0 = &ring[w][0][0][lane];
    const short8* const rring1 = &ring[w][1][0][lane];
    char* const rdst0 = (char*)&ring[w][0][0][0];
    char* const rdst1 = (char*)&ring[w][1][0][0];

#pragma unroll 1
    for (int step = 0; step < NSTEPS; ++step){
        barrier_lgkm();                        // (A) x_lds stable

        // last-step pruning: only d-tile 3 feeds out dims 120..123
        const bool active = (step < NSTEPS - 1) || (t == 3);

        const short8* ap = Aw;
        short8 abuf[9];
        if (active){
            // DMA pair-0 staged slots (oldest batch -- fenced below)
#pragma unroll
            for (int s2 = 0; s2 < 4; ++s2)
                GLL(Aw + s2 * 64, rdst0 + s2 * 1024);
            asm volatile("" ::: "memory");     // pin: pair-0 DMAs oldest
            // direct pair-0 slots 4..8 + DMA pair-1 staged slots
#pragma unroll
            for (int s = 4; s < 9; ++s) abuf[s] = Aw[s * 64];
#pragma unroll
            for (int s2 = 0; s2 < 4; ++s2)
                GLL(Aw + (9 + s2) * 64, rdst1 + s2 * 1024);
            ap = Aw + 9 * 64;                  // direct cursor -> pair 1
        }

        // ---- build bpack (1024 frags, 2 per thread) while loads fly ----
#pragma unroll
        for (int f0 = 0; f0 < 2; ++f0){
            int f  = tid + f0 * 512;
            int gg = f >> 9, s = (f >> 6) & 7, l = f & 63;
            int c  = gg * 32 + (l & 31);
            int jb = 16 * s + 8 * (l >> 5);
            union { short8 v; unsigned short u[8]; } fr;
#pragma unroll
            for (int e = 0; e < 8; ++e)
                fr.u[e] = f2bf(x_lds[(jb + e) * BT + c]);
            bpack[f] = fr.v;
        }

        // ---- acc: g0 carries x_old + W0 for both groups; g1 pure partial ----
        f32x16 acc0, acc1;
        if (active){
            if (g == 0){
#pragma unroll
                for (int r = 0; r < 16; ++r){
                    int d = 32 * t + (r & 3) + 8 * (r >> 2) + 4 * hi;
                    acc0[r] = x_lds[d * BT + ln]      + w0_lds[d];
                    acc1[r] = x_lds[d * BT + 32 + ln] + w0_lds[d];
                }
            } else {
#pragma unroll
                for (int r = 0; r < 16; ++r){ acc0[r] = 0.f; acc1[r] = 0.f; }
            }
        }

        barrier_lgkm();                        // (B) bpack visible

        if (active){
            short8 bfrag0[8], bfrag1[8];       // B reg-cache for current BK block

            // Invariant at each pair-q top: ap -> pair q+1; abuf[4..8] hold
            // pair q's direct slices (loaded last body); ring[q&1] holds pair
            // q's staged slices (DMA'd 2 bodies ago). Body issues exactly
            // 5 direct + 4 DMA vmem ops -> vmcnt(9) waits the q-2 DMA batch.
#define PAIRS(BK, NQ, LASTB)                                                    \
            {                                                                   \
                _Pragma("unroll")                                               \
                for (int s = 0; s < 8 - (BK); ++s){                             \
                    bfrag0[s] = bpack[((BK) + s) * 64 + lane];                  \
                    bfrag1[s] = bpack[512 + ((BK) + s) * 64 + lane];            \
                }                                                               \
                _Pragma("unroll 2")                                             \
                for (int q = 0; q < (NQ); ++q){                                 \
                    const int p = 16 * (BK) + q;                                \
                    asm volatile("s_waitcnt vmcnt(9)" ::: "memory");            \
                    const short8* rp = ((p) & 1) ? rring1 : rring0;             \
                    abuf[0] = rp[0];   abuf[1] = rp[64];                        \
                    abuf[2] = rp[128]; abuf[3] = rp[192];                       \
                    float s0a = x_lds[p * BT + ln];                             \
                    float s0b = x_lds[p * BT + 32 + ln];                        \
                    float s1a = x_lds[(127 - p) * BT + ln];                     \
                    float s1b = x_lds[(127 - p) * BT + 32 + ln];                \
                    f32x16 Y0, Y1;                                              \
                    Y0 = __builtin_amdgcn_mfma_f32_32x32x16_bf16(abuf[4], bfrag0[4], zero16, 0, 0, 0); \
                    Y1 = __builtin_amdgcn_mfma_f32_32x32x16_bf16(abuf[4], bfrag1[4], zero16, 0, 0, 0); \
                    abuf[4] = ap[4 * 64];                                       \
                    _Pragma("unroll")                                           \
                    for (int s = 5; s < 8 - (BK); ++s){                         \
                        Y0 = __builtin_amdgcn_mfma_f32_32x32x16_bf16(abuf[s], bfrag0[s], Y0, 0, 0, 0); \
                        Y1 = __builtin_amdgcn_mfma_f32_32x32x16_bf16(abuf[s], bfrag1[s], Y1, 0, 0, 0); \
                        abuf[s] = ap[s * 64];                                   \
                    }                                                           \
                    _Pragma("unroll")                                           \
                    for (int s = 0; s < 4; ++s){                                \
                        Y0 = __builtin_amdgcn_mfma_f32_32x32x16_bf16(abuf[s], bfrag0[s], Y0, 0, 0, 0); \
                        Y1 = __builtin_amdgcn_mfma_f32_32x32x16_bf16(abuf[s], bfrag1[s], Y1, 0, 0, 0); \
                    }                                                           \
                    acc0 += s0a * Y0;                                           \
                    acc1 += s0b * Y1;                                           \
                    f32x16 Z0, Z1;                                              \
                    _Pragma("unroll")                                           \
                    for (int s = 0; s < 1 + (BK); ++s){                         \
                        Z0 = __builtin_amdgcn_mfma_f32_32x32x16_bf16(abuf[8 - (BK) + s], bfrag0[7 - 2 * (BK) + s], s ? Z0 : zero16, 0, 0, 0); \
                        Z1 = __builtin_amdgcn_mfma_f32_32x32x16_bf16(abuf[8 - (BK) + s], bfrag1[7 - 2 * (BK) + s], s ? Z1 : zero16, 0, 0, 0); \
                        abuf[8 - (BK) + s] = ap[(8 - (BK) + s) * 64];           \
                    }                                                           \
                    acc0 += s1a * Z0;                                           \
                    acc1 += s1b * Z1;                                           \
                    {                                                           \
                        /* DMA pair q+2 staged slots -> ring[q&1] (slot just  */\
                        /* consumed; its ds_reads completed at this pair top).*/\
                        /* LASTB final pair: dummy refetch of own slice 0..3  */\
                        /* (keeps the vmcnt count; avoids OOB past the array).*/\
                        const short8* gsrc = ((LASTB) && q == (NQ) - 1)         \
                                           ? Aw : (ap + 9 * 64);                \
                        char* ldst = ((p) & 1) ? rdst1 : rdst0;                 \
                        _Pragma("unroll")                                       \
                        for (int s2 = 0; s2 < 4; ++s2)                          \
                            GLL(gsrc + s2 * 64, ldst + s2 * 1024);              \
                    }                                                           \
                    ap += 9 * 64;                                               \
                }                                                               \
            }

            if (g == 0){
                PAIRS(0, 16, 0)
                PAIRS(1, 16, 0)
                // pair 31's trailing direct/DMA reads land in pairs 32/33
                // (g1's region -- valid, discarded)
            } else {
                PAIRS(2, 16, 0)
                PAIRS(3, 16, 1)
                // ---- linear (W1) row == "pair 64": staged 0..3 from ring[0]
                // (DMA'd at pair 62), direct 4..8 = slices 580..584 loaded
                // during pair 63. scale==1 -> accumulate via MFMA C-operand.
                asm volatile("s_waitcnt vmcnt(9)" ::: "memory");
                abuf[0] = rring0[0];   abuf[1] = rring0[64];
                abuf[2] = rring0[128]; abuf[3] = rring0[192];
#pragma unroll
                for (int s = 0; s < 8; ++s){
                    bfrag0[s] = bpack[s * 64 + lane];
                    bfrag1[s] = bpack[512 + s * 64 + lane];
                }
#pragma unroll
                for (int s = 0; s < 8; ++s){
                    acc0 = __builtin_amdgcn_mfma_f32_32x32x16_bf16(abuf[s], bfrag0[s], acc0, 0, 0, 0);
                    acc1 = __builtin_amdgcn_mfma_f32_32x32x16_bf16(abuf[s], bfrag1[s], acc1, 0, 0, 0);
                }
                // publish K-half partials
#pragma unroll
                for (int r = 0; r < 16; ++r){
                    sc_lds[0][(t * 64 + lane) * 17 + r] = acc0[r];
                    sc_lds[1][(t * 64 + lane) * 17 + r] = acc1[r];
                }
            }
#undef PAIRS
        }

        barrier_lgkm();                        // (C) reads done + scratch visible
        if (active && g == 0){
#pragma unroll
            for (int r = 0; r < 16; ++r){
                acc0[r] += sc_lds[0][(t * 64 + lane) * 17 + r];
                acc1[r] += sc_lds[1][(t * 64 + lane) * 17 + r];
            }
            if (step < NSTEPS - 1){
#pragma unroll
                for (int r = 0; r < 16; ++r){
                    int d = 32 * t + (r & 3) + 8 * (r >> 2) + 4 * hi;
                    x_lds[d * BT + ln]      = acc0[r];
                    x_lds[d * BT + 32 + ln] = acc1[r];
                }
            } else if (hi == 0){
                // out dims 120..123 -> tile 3, regs 12..15 @ hi==0
                *(float4*)(out + (size_t)(b0 + ln) * 4) =
                    make_float4(acc0[12], acc0[13], acc0[14], acc0[15]);
                *(float4*)(out + (size_t)(b0 + 32 + ln) * 4) =
                    make_float4(acc1[12], acc1[13], acc1[14], acc1[15]);
            }
        }
        // next iteration's barrier (A) orders g0's x write vs g1's next reads
    }
}

extern "C" void kernel_launch(void* const* d_in, const int* in_sizes, int n_in,
                              void* d_out, int out_size, void* d_ws, size_t ws_size,
                              hipStream_t stream)
{
    const float* X  = (const float*)d_in[0];
    const float* W  = (const float*)d_in[1];
    const float* ti = (const float*)d_in[2];
    const float* li = (const float*)d_in[3];
    float* out      = (float*)d_out;
    short8* A       = (short8*)d_ws;           // 4*585*64*16 B = 2.40 MB

    const int ntotal = 4 * 130 * 8 * 64;
    prep_kernel<<<(ntotal + 255) / 256, 256, 0, stream>>>(W, A);
    taylor_kernel<<<BATCH / BT, 512, 0, stream>>>(X, W, ti, li, A, out);
}